// Round 4
// baseline (115.783 us; speedup 1.0000x reference)
//
#include <hip/hip_runtime.h>
#include <stdint.h>

// ScatterND (k=1): out = data.copy(); out[indices[i]] = updates[i]
// data: [1000000,64] f32   indices: [100000,1] i32   updates: [100000,64] f32
//
// Inverse-permutation plan (out written once, sequentially):
//   1. hipMemsetAsync(perm, 0xFF)          -> perm[row] = -1        (4 MB)
//   2. scatter_perm: perm[idx[i]] = i      (100k x 4 B random writes)
//   3. fused_write: out[i] = (perm[row]>=0 ? updates[perm] : data)[...]
//      per-lane pointer select (no divergent branch), nontemporal ld/st.

typedef float f32x4 __attribute__((ext_vector_type(4)));  // clang vector: OK for nontemporal builtins

__global__ void scatter_perm_kernel(const int* __restrict__ idx,
                                    int* __restrict__ perm, int n) {
    int t = blockIdx.x * blockDim.x + threadIdx.x;
    if (t < n) perm[idx[t]] = t;
}

__global__ __launch_bounds__(256) void fused_write_kernel(
    const f32x4* __restrict__ data,
    const f32x4* __restrict__ upd,
    const int* __restrict__ perm,
    f32x4* __restrict__ out,
    size_t n4) {
    const size_t stride = (size_t)gridDim.x * blockDim.x;
    size_t i = (size_t)blockIdx.x * blockDim.x + threadIdx.x;

    // 4x unrolled grid-stride: 4 independent perm loads, then 4 independent
    // data/update loads, then 4 streaming stores.
    for (; i + 3 * stride < n4; i += 4 * stride) {
        const size_t i0 = i, i1 = i + stride, i2 = i + 2 * stride, i3 = i + 3 * stride;
        const int j0 = perm[i0 >> 4];
        const int j1 = perm[i1 >> 4];
        const int j2 = perm[i2 >> 4];
        const int j3 = perm[i3 >> 4];
        // Per-lane pointer select: one load path, no exec-mask divergence.
        const f32x4* s0 = (j0 >= 0) ? (upd + ((size_t)j0 * 16 + (i0 & 15))) : (data + i0);
        const f32x4* s1 = (j1 >= 0) ? (upd + ((size_t)j1 * 16 + (i1 & 15))) : (data + i1);
        const f32x4* s2 = (j2 >= 0) ? (upd + ((size_t)j2 * 16 + (i2 & 15))) : (data + i2);
        const f32x4* s3 = (j3 >= 0) ? (upd + ((size_t)j3 * 16 + (i3 & 15))) : (data + i3);
        f32x4 v0 = __builtin_nontemporal_load(s0);
        f32x4 v1 = __builtin_nontemporal_load(s1);
        f32x4 v2 = __builtin_nontemporal_load(s2);
        f32x4 v3 = __builtin_nontemporal_load(s3);
        __builtin_nontemporal_store(v0, out + i0);
        __builtin_nontemporal_store(v1, out + i1);
        __builtin_nontemporal_store(v2, out + i2);
        __builtin_nontemporal_store(v3, out + i3);
    }
    for (; i < n4; i += stride) {
        const int j = perm[i >> 4];
        const f32x4* s = (j >= 0) ? (upd + ((size_t)j * 16 + (i & 15))) : (data + i);
        __builtin_nontemporal_store(__builtin_nontemporal_load(s), out + i);
    }
}

// Fallback (ws too small): plain copy then scatter.
__global__ void copy_all_kernel(const f32x4* __restrict__ src,
                                f32x4* __restrict__ dst, size_t n4) {
    size_t i = (size_t)blockIdx.x * blockDim.x + threadIdx.x;
    const size_t stride = (size_t)gridDim.x * blockDim.x;
    for (; i < n4; i += stride) dst[i] = src[i];
}

__global__ void scatter_kernel(const int* __restrict__ idx,
                               const f32x4* __restrict__ upd,
                               f32x4* __restrict__ out, size_t total4) {
    size_t i = (size_t)blockIdx.x * blockDim.x + threadIdx.x;
    const size_t stride = (size_t)gridDim.x * blockDim.x;
    for (; i < total4; i += stride) {
        const size_t row = i >> 4;
        const size_t col = i & 15;
        const int r = idx[row];
        out[(size_t)r * 16 + col] = upd[i];
    }
}

extern "C" void kernel_launch(void* const* d_in, const int* in_sizes, int n_in,
                              void* d_out, int out_size, void* d_ws, size_t ws_size,
                              hipStream_t stream) {
    const float* data    = (const float*)d_in[0];
    const int*   indices = (const int*)d_in[1];
    const float* updates = (const float*)d_in[2];
    float* out = (float*)d_out;

    const size_t n4          = (size_t)out_size / 4;      // 16M float4
    const size_t num_rows    = (size_t)out_size / 64;     // 1,000,000
    const size_t num_updates = (size_t)in_sizes[2] / 64;  // 100,000

    const int block = 256;
    auto grid_for = [&](size_t work) {
        size_t g = (work + block - 1) / block;
        if (g > 2048) g = 2048;
        return (int)g;
    };

    if (ws_size >= num_rows * sizeof(int)) {
        int* perm = (int*)d_ws;
        // perm[row] = -1 for all rows (0xFFFFFFFF bytes == -1 as int32).
        (void)hipMemsetAsync(perm, 0xFF, num_rows * sizeof(int), stream);
        scatter_perm_kernel<<<grid_for(num_updates), block, 0, stream>>>(
            indices, perm, (int)num_updates);
        fused_write_kernel<<<grid_for(n4 / 4), block, 0, stream>>>(
            (const f32x4*)data, (const f32x4*)updates, perm, (f32x4*)out, n4);
    } else {
        const size_t total4 = num_updates * 16;
        copy_all_kernel<<<grid_for(n4), block, 0, stream>>>(
            (const f32x4*)data, (f32x4*)out, n4);
        scatter_kernel<<<grid_for(total4), block, 0, stream>>>(
            indices, (const f32x4*)updates, (f32x4*)out, total4);
    }
}

// Round 5
// 113.300 us; speedup vs baseline: 1.0219x; 1.0219x over previous
//
#include <hip/hip_runtime.h>
#include <stdint.h>

// ScatterND (k=1): out = data.copy(); out[indices[i]] = updates[i]
// data: [1000000,64] f32   indices: [100000,1] i32   updates: [100000,64] f32
//
// R5 plan: use the runtime's tuned D2D copy (hipMemcpyAsync is graph-capture
// legal per harness docs) for the 256 MB bulk copy, then one small scatter
// kernel (52 MB) stream-ordered after it. 2 graph nodes total.

typedef float f32x4 __attribute__((ext_vector_type(4)));

__global__ __launch_bounds__(256) void scatter_kernel(
    const int* __restrict__ idx,
    const f32x4* __restrict__ upd,
    f32x4* __restrict__ out,
    size_t total4) {
    // Thread i handles float4 #(i&15) of update-row #(i>>4); the 16 threads
    // sharing a row load the same index (L1-broadcast).
    size_t i = (size_t)blockIdx.x * blockDim.x + threadIdx.x;
    const size_t stride = (size_t)gridDim.x * blockDim.x;
    for (; i < total4; i += stride) {
        const size_t row = i >> 4;
        const size_t col = i & 15;
        const int r = idx[row];
        out[(size_t)r * 16 + col] = upd[i];
    }
}

extern "C" void kernel_launch(void* const* d_in, const int* in_sizes, int n_in,
                              void* d_out, int out_size, void* d_ws, size_t ws_size,
                              hipStream_t stream) {
    const float* data    = (const float*)d_in[0];
    const int*   indices = (const int*)d_in[1];
    const float* updates = (const float*)d_in[2];
    float* out = (float*)d_out;

    const size_t num_updates = (size_t)in_sizes[2] / 64;  // 100,000
    const size_t total4      = num_updates * 16;          // 1.6M float4

    // Bulk copy: runtime-tuned D2D path.
    (void)hipMemcpyAsync(out, data, (size_t)out_size * sizeof(float),
                         hipMemcpyDeviceToDevice, stream);

    // Scatter updates over the copied rows (stream-ordered after the copy).
    const int block = 256;
    size_t g = (total4 + block - 1) / block;
    if (g > 2048) g = 2048;
    scatter_kernel<<<(int)g, block, 0, stream>>>(
        indices, (const f32x4*)updates, (f32x4*)out, total4);
}